// Round 7
// baseline (314.845 us; speedup 1.0000x reference)
//
#include <hip/hip_runtime.h>

#define DIM 640
#define NHEADS 10
#define HDIM 64
#define SEQ 1024
#define BATCH 16
#define MROWS (BATCH * SEQ)   // 16384
#define QKVN (3 * DIM)        // 1920
#define NBH (BATCH * NHEADS)  // 160

typedef float f32x4 __attribute__((ext_vector_type(4)));
typedef __bf16 bf16x8 __attribute__((ext_vector_type(8)));
typedef short s16x4 __attribute__((ext_vector_type(4)));

// 640^-0.5 * log2(e) — folded into Q at K1 epilogue
#define SM_C 0.057027536f

// hardware bf16 convert (v_cvt_pk_bf16_f32 on gfx950), RNE
__device__ __forceinline__ unsigned short f2b(float f) {
  union { __bf16 h; unsigned short u; } v;
  v.h = (__bf16)f;
  return v.u;
}

__device__ __forceinline__ f32x4 mfma16(bf16x8 a, bf16x8 b, f32x4 c) {
  return __builtin_amdgcn_mfma_f32_16x16x32_bf16(a, b, c, 0, 0, 0);
}
// K=16 variant: A/B are 4 bf16 (2 VGPRs). A-fragment comes straight out of
// S^T's C-layout (no LDS round-trip).
__device__ __forceinline__ f32x4 mfma1k(s16x4 a, s16x4 b, f32x4 c) {
  return __builtin_amdgcn_mfma_f32_16x16x16bf16_1k(a, b, c, 0, 0, 0);
}

// async global->LDS, 16B per lane. dest base wave-uniform; lane i lands at
// dest + i*16B. XOR swizzle is encoded in the per-lane SOURCE address.
typedef __attribute__((address_space(3))) unsigned int as3_u32;
typedef const __attribute__((address_space(1))) unsigned int as1_u32;
__device__ __forceinline__ void glds16(const unsigned short* g, unsigned short* l) {
  __builtin_amdgcn_global_load_lds((as1_u32*)g, (as3_u32*)l, 16, 0, 0);
}

// ---------------------------------------------------------------------------
// K0: fused prep. Sections by blockIdx.x:
//   [0, 10240)            : x fp32 -> bf16 (4 elem/thread)
//   [10240, 11440)        : w_qkv [640][1920] -> wt_qkv [1920][640] bf16
//   [11440, 11840)        : w_out [640][640]  -> wt_out [640][640]  bf16
// ---------------------------------------------------------------------------
#define NCONV 10240
#define NT1 1200   // (1920/32)*(640/32)
#define NT2 400    // (640/32)*(640/32)

__global__ __launch_bounds__(256) void prep_kernel(
    const float* __restrict__ X, unsigned short* __restrict__ xb,
    const float* __restrict__ Wq, unsigned short* __restrict__ Wtq,
    const float* __restrict__ Wo, unsigned short* __restrict__ Wto) {
  __shared__ int tile[32][33];
  const int b = blockIdx.x, t = threadIdx.x;
  if (b < NCONV) {
    int i = (b * 256 + t) * 4;
    float4 v = *(const float4*)(X + i);
    ushort4 s;
    s.x = f2b(v.x); s.y = f2b(v.y); s.z = f2b(v.z); s.w = f2b(v.w);
    *(ushort4*)(xb + i) = s;
    return;
  }
  const float* W;
  unsigned short* Wt;
  int R = DIM, C, bb;
  if (b < NCONV + NT1) { bb = b - NCONV; W = Wq; Wt = Wtq; C = QKVN; }
  else                 { bb = b - NCONV - NT1; W = Wo; Wt = Wto; C = DIM; }
  const int nbx = C / 32;
  const int c0 = (bb % nbx) * 32, r0 = (bb / nbx) * 32;
  const int tx = t & 31, ty = t >> 5;
#pragma unroll
  for (int i = 0; i < 4; ++i)
    tile[ty + 8 * i][tx] = f2b(W[(r0 + ty + 8 * i) * C + c0 + tx]);
  __syncthreads();
#pragma unroll
  for (int i = 0; i < 4; ++i)
    Wt[(c0 + ty + 8 * i) * R + r0 + tx] = (unsigned short)tile[tx][ty + 8 * i];
}

// ---------------------------------------------------------------------------
// K1: qkv = xb @ w_qkv^T-staged + b. A staged via glds into XOR-swizzled LDS;
// B-fragments loaded DIRECT from global (L2-resident, 16B/lane contiguous).
// Scatters Q (pre-scaled by SM_C), K into [bh][n][64]; V into [bh][64][n].
// ---------------------------------------------------------------------------
__global__ __launch_bounds__(256) void qkv_gemm(
    const unsigned short* __restrict__ A, const unsigned short* __restrict__ Bt,
    const float* __restrict__ bias,
    unsigned short* __restrict__ qw, unsigned short* __restrict__ kw,
    unsigned short* __restrict__ vtw) {
  __shared__ __attribute__((aligned(16))) unsigned short As[128 * 64];
  const int t = threadIdx.x;
  const int lane = t & 63, w = t >> 6;
  const int quad = lane >> 4, cl = lane & 15;
  const int m0 = blockIdx.y * 128, n0 = blockIdx.x * 128;
  const int wr = (w >> 1) * 64, wc = (w & 1) * 64;

  const int r8 = lane >> 3;
  const int sw = ((lane & 7) ^ r8) * 8;
  const unsigned short* asrc = A + (size_t)(m0 + w * 32 + r8) * DIM + sw;

  const int x = cl & 7;
  const int aoff0 = (wr + cl) * 64 + (quad ^ x) * 8;
  const int aoff1 = (wr + cl) * 64 + ((4 + quad) ^ x) * 8;

  // direct-global B fragment base pointers (row n0+wc+j*16+cl, k-chunk quad*8)
  const unsigned short* bp0 = Bt + (size_t)(n0 + wc + cl) * DIM + quad * 8;

  f32x4 acc[4][4];
#pragma unroll
  for (int i = 0; i < 4; ++i)
#pragma unroll
    for (int j = 0; j < 4; ++j) acc[i][j] = (f32x4){0.f, 0.f, 0.f, 0.f};

  for (int kt = 0; kt < DIM / 64; ++kt) {
    __syncthreads();
#pragma unroll
    for (int i = 0; i < 4; ++i)
      glds16(asrc + (size_t)i * 8 * DIM, &As[(w * 32 + i * 8) * 64]);
    asrc += 64;
    __syncthreads();
#pragma unroll
    for (int ks = 0; ks < 2; ++ks) {
      const int ao = ks ? aoff1 : aoff0;
      const int ko = kt * 64 + ks * 32;
      bf16x8 af[4], bfr[4];
#pragma unroll
      for (int j = 0; j < 4; ++j)
        bfr[j] = *(const bf16x8*)(bp0 + (size_t)j * 16 * DIM + ko);
#pragma unroll
      for (int i = 0; i < 4; ++i) af[i] = *(const bf16x8*)&As[ao + i * 1024];
#pragma unroll
      for (int i = 0; i < 4; ++i)
#pragma unroll
        for (int j = 0; j < 4; ++j) acc[i][j] = mfma16(af[i], bfr[j], acc[i][j]);
    }
  }

  const int sec = n0 / DIM;  // 0=q, 1=k, 2=v (block-uniform)
  unsigned short* qk = (sec == 0) ? qw : kw;
  const float sc = (sec == 0) ? SM_C : 1.0f;  // fold softmax scale into Q
#pragma unroll
  for (int j = 0; j < 4; ++j) {
    int cc = n0 + wc + j * 16 + cl;
    int cr = cc - sec * DIM;
    int h = cr >> 6, d = cr & 63;
    float bv = bias[cc];
#pragma unroll
    for (int i = 0; i < 4; ++i) {
      int rbase = m0 + wr + i * 16 + quad * 4;
      int b = rbase >> 10, n = rbase & 1023;
      int bh = b * NHEADS + h;
      if (sec < 2) {
        size_t base = ((size_t)bh * SEQ + n) * HDIM + d;
#pragma unroll
        for (int r = 0; r < 4; ++r)
          qk[base + (size_t)r * HDIM] = f2b((acc[i][j][r] + bv) * sc);
      } else {
        ushort4 s;
        s.x = f2b(acc[i][j][0] + bv);
        s.y = f2b(acc[i][j][1] + bv);
        s.z = f2b(acc[i][j][2] + bv);
        s.w = f2b(acc[i][j][3] + bv);
        *(ushort4*)(vtw + ((size_t)bh * HDIM + d) * SEQ + n) = s;
      }
    }
  }
}

// ---------------------------------------------------------------------------
// K2: flash attention (unchanged from R6). S^T = mfma(K_frag, Q_frag) ->
// exp2 in-register -> K=16 PV MFMAs. K/V double-buffered via glds.
// Grid flat = bh + 160*qb -> XCD affinity.
// ---------------------------------------------------------------------------
__global__ __launch_bounds__(256) void attn_kernel(
    const unsigned short* __restrict__ qw, const unsigned short* __restrict__ kw,
    const unsigned short* __restrict__ vtw, unsigned short* __restrict__ out) {
  __shared__ __attribute__((aligned(16))) unsigned short Ks[2][64 * 64];
  __shared__ __attribute__((aligned(16))) unsigned short Vs[2][64 * 64];
  const int t = threadIdx.x;
  const int lane = t & 63, w = t >> 6;
  const int quad = lane >> 4, cl = lane & 15;
  const int flat = blockIdx.x;
  const int bh = flat % NBH;     // flat % 8 == bh % 8 -> XCD affinity
  const int qb = flat / NBH;     // 0..7
  const size_t qkbase = (size_t)bh * SEQ * HDIM;
  const size_t vbase  = (size_t)bh * HDIM * SEQ;

  const int r8 = lane >> 3;
  const int sw = ((lane & 7) ^ r8) * 8;
  const unsigned short* ksrc = kw + qkbase + (size_t)(w * 16 + r8) * HDIM + sw;
  const unsigned short* vsrc = vtw + vbase + (size_t)(w * 16 + r8) * SEQ + sw;

  const int x = cl & 7;
  const int koff0 = cl * 64 + (quad ^ x) * 8;        // k 0..31
  const int koff1 = cl * 64 + ((4 + quad) ^ x) * 8;  // k 32..63

  bf16x8 aq[2][2];
#pragma unroll
  for (int i = 0; i < 2; ++i) {
    const unsigned short* qp =
        qw + qkbase + (size_t)(qb * 128 + w * 32 + i * 16 + cl) * HDIM;
    aq[i][0] = *(const bf16x8*)(qp + quad * 8);
    aq[i][1] = *(const bf16x8*)(qp + 32 + quad * 8);
  }

  const s16x4 ones4 = {0x3F80, 0x3F80, 0x3F80, 0x3F80};  // bf16 1.0 x4

  f32x4 o_acc[2][4];
#pragma unroll
  for (int i = 0; i < 2; ++i)
#pragma unroll
    for (int dt = 0; dt < 4; ++dt) o_acc[i][dt] = (f32x4){0.f, 0.f, 0.f, 0.f};
  f32x4 o1[2];
  o1[0] = (f32x4){0.f, 0.f, 0.f, 0.f};
  o1[1] = (f32x4){0.f, 0.f, 0.f, 0.f};

  glds16(ksrc,            &Ks[0][(w * 16) * 64]);
  glds16(ksrc + 8 * HDIM, &Ks[0][(w * 16 + 8) * 64]);
  glds16(vsrc,            &Vs[0][(w * 16) * 64]);
  glds16(vsrc + 8 * SEQ,  &Vs[0][(w * 16 + 8) * 64]);

  for (int kt = 0; kt < 16; ++kt) {
    const int cur = kt & 1, nxt = cur ^ 1;
    __syncthreads();               // drains vmcnt: tile kt resident in buf cur

    if (kt < 15) {                 // prefetch tile kt+1 into buf nxt
      const unsigned short* kp = ksrc + (size_t)(kt + 1) * 64 * HDIM;
      const unsigned short* vp = vsrc + (kt + 1) * 64;
      glds16(kp,            &Ks[nxt][(w * 16) * 64]);
      glds16(kp + 8 * HDIM, &Ks[nxt][(w * 16 + 8) * 64]);
      glds16(vp,            &Vs[nxt][(w * 16) * 64]);
      glds16(vp + 8 * SEQ,  &Vs[nxt][(w * 16 + 8) * 64]);
    }

    const unsigned short* Kc = &Ks[cur][0];
    const unsigned short* Vc = &Vs[cur][0];

    s16x4 pf[2][4];                // [q-tile][kv-chunk16]
#pragma unroll
    for (int jj = 0; jj < 4; ++jj) {
      bf16x8 bk0 = *(const bf16x8*)&Kc[koff0 + jj * 1024];
      bf16x8 bk1 = *(const bf16x8*)&Kc[koff1 + jj * 1024];
#pragma unroll
      for (int i = 0; i < 2; ++i) {
        f32x4 z = (f32x4){0.f, 0.f, 0.f, 0.f};
        z = mfma16(bk0, aq[i][0], z);   // A=K, B=Q  ->  S^T
        z = mfma16(bk1, aq[i][1], z);
        s16x4 p;
#pragma unroll
        for (int r = 0; r < 4; ++r)
          p[r] = (short)f2b(__builtin_amdgcn_exp2f(z[r]));
        pf[i][jj] = p;
        o1[i] = mfma1k(p, ones4, o1[i]);
      }
    }

#pragma unroll
    for (int dt = 0; dt < 4; ++dt) {
      const int vrow = dt * 16 + cl;
      const int vbase_off = vrow * 64 + (quad & 1) * 4;
      const int vxor = vrow & 7;
#pragma unroll
      for (int jj = 0; jj < 4; ++jj) {
        s16x4 bv = *(const s16x4*)
            &Vc[vbase_off + ((2 * jj + (quad >> 1)) ^ vxor) * 8];
#pragma unroll
        for (int i = 0; i < 2; ++i)
          o_acc[i][dt] = mfma1k(pf[i][jj], bv, o_acc[i][dt]);
      }
    }
  }

  const int b = bh / NHEADS, h = bh % NHEADS;
#pragma unroll
  for (int i = 0; i < 2; ++i)
#pragma unroll
    for (int r = 0; r < 4; ++r) {
      float inv = 1.f / o1[i][r];
      int row = b * SEQ + qb * 128 + w * 32 + i * 16 + quad * 4 + r;
#pragma unroll
      for (int dt = 0; dt < 4; ++dt)
        out[(size_t)row * DIM + h * HDIM + dt * 16 + cl] =
            f2b(o_acc[i][dt][r] * inv);
    }
}

// ---------------------------------------------------------------------------
// K3: out = attn @ w_out + b_out. fp32 output. A via glds, B direct-global.
// ---------------------------------------------------------------------------
__global__ __launch_bounds__(256) void out_gemm(
    const unsigned short* __restrict__ A, const unsigned short* __restrict__ Bt,
    const float* __restrict__ bias, float* __restrict__ C) {
  __shared__ __attribute__((aligned(16))) unsigned short As[128 * 64];
  const int t = threadIdx.x;
  const int lane = t & 63, w = t >> 6;
  const int quad = lane >> 4, cl = lane & 15;
  const int m0 = blockIdx.y * 128, n0 = blockIdx.x * 128;
  const int wr = (w >> 1) * 64, wc = (w & 1) * 64;

  const int r8 = lane >> 3;
  const int sw = ((lane & 7) ^ r8) * 8;
  const unsigned short* asrc = A + (size_t)(m0 + w * 32 + r8) * DIM + sw;

  const int x = cl & 7;
  const int aoff0 = (wr + cl) * 64 + (quad ^ x) * 8;
  const int aoff1 = (wr + cl) * 64 + ((4 + quad) ^ x) * 8;

  const unsigned short* bp0 = Bt + (size_t)(n0 + wc + cl) * DIM + quad * 8;

  f32x4 acc[4][4];
#pragma unroll
  for (int i = 0; i < 4; ++i)
#pragma unroll
    for (int j = 0; j < 4; ++j) acc[i][j] = (f32x4){0.f, 0.f, 0.f, 0.f};

  for (int kt = 0; kt < DIM / 64; ++kt) {
    __syncthreads();
#pragma unroll
    for (int i = 0; i < 4; ++i)
      glds16(asrc + (size_t)i * 8 * DIM, &As[(w * 32 + i * 8) * 64]);
    asrc += 64;
    __syncthreads();
#pragma unroll
    for (int ks = 0; ks < 2; ++ks) {
      const int ao = ks ? aoff1 : aoff0;
      const int ko = kt * 64 + ks * 32;
      bf16x8 af[4], bfr[4];
#pragma unroll
      for (int j = 0; j < 4; ++j)
        bfr[j] = *(const bf16x8*)(bp0 + (size_t)j * 16 * DIM + ko);
#pragma unroll
      for (int i = 0; i < 4; ++i) af[i] = *(const bf16x8*)&As[ao + i * 1024];
#pragma unroll
      for (int i = 0; i < 4; ++i)
#pragma unroll
        for (int j = 0; j < 4; ++j) acc[i][j] = mfma16(af[i], bfr[j], acc[i][j]);
    }
  }
#pragma unroll
  for (int j = 0; j < 4; ++j) {
    int cc = n0 + wc + j * 16 + cl;
    float bv = bias[cc];
#pragma unroll
    for (int i = 0; i < 4; ++i) {
#pragma unroll
      for (int r = 0; r < 4; ++r) {
        int rr = m0 + wr + i * 16 + quad * 4 + r;
        C[(size_t)rr * DIM + cc] = acc[i][j][r] + bv;
      }
    }
  }
}

// ---------------------------------------------------------------------------
extern "C" void kernel_launch(void* const* d_in, const int* in_sizes, int n_in,
                              void* d_out, int out_size, void* d_ws, size_t ws_size,
                              hipStream_t stream) {
  const float* x     = (const float*)d_in[0];
  const float* w_qkv = (const float*)d_in[1];
  const float* b_qkv = (const float*)d_in[2];
  const float* w_out = (const float*)d_in[3];
  const float* b_out = (const float*)d_in[4];
  float* out = (float*)d_out;

  unsigned short* ws = (unsigned short*)d_ws;
  unsigned short* xb      = ws;                          // 10,485,760 (aliased w/ attn_ws)
  unsigned short* wt_qkv  = ws + 10485760;               // 1,228,800
  unsigned short* wt_out  = wt_qkv + 1228800;            // 409,600
  unsigned short* qw      = wt_out + 409600;             // 10,485,760
  unsigned short* kw      = qw + 10485760;               // 10,485,760
  unsigned short* vtw     = kw + 10485760;               // 10,485,760
  unsigned short* attn_ws = xb;                          // alias: xb dead after K1

  prep_kernel<<<NCONV + NT1 + NT2, 256, 0, stream>>>(x, xb, w_qkv, wt_qkv, w_out, wt_out);
  qkv_gemm<<<dim3(QKVN / 128, MROWS / 128), 256, 0, stream>>>(xb, wt_qkv, b_qkv, qw, kw, vtw);
  attn_kernel<<<dim3(NBH * (SEQ / 128)), 256, 0, stream>>>(qw, kw, vtw, attn_ws);
  out_gemm<<<dim3(DIM / 128, MROWS / 128), 256, 0, stream>>>(attn_ws, wt_out, b_out, out);
}